// Round 4
// baseline (160.241 us; speedup 1.0000x reference)
//
#include <hip/hip_runtime.h>
#include <hip/hip_fp16.h>
#include <math.h>

constexpr int kNodes = 50000;
constexpr int kEdges = 600000;
constexpr int kF     = 128;
constexpr int kNPB   = 64;        // nodes per block in gemm phase (4 waves x 16)
constexpr int kCap   = 48;        // fixed bucket capacity; P(deg>=48) ~ 3e-15/node
constexpr int kCurStride = 16;    // one 64B cache line per cursor counter (R3)
constexpr int kEPT   = 4;         // edges per thread in fill (R4)

constexpr int kGemmB = (kNodes + kNPB - 1) / kNPB;            // 782
constexpr int kFillB = (kEdges + 256 * kEPT - 1) / (256 * kEPT); // 586

// workspace layout (bytes)
constexpr size_t kOffWt     = 0;                                          // 64 KB region (Wfrag f16 = 32 KB)
constexpr size_t kOffCursor = 65536;                                      // 50000*64B = 3.2 MB padded counters
constexpr size_t kOffBucket = kOffCursor + (size_t)kNodes * kCurStride * 4; // ushort bucket, 4.8 MB
constexpr size_t kOffGpk    = kOffBucket + (size_t)kNodes * kCap * 2;     // 16B-aligned (4.8M%16==0)
constexpr size_t kWsNeeded  = kOffGpk + (size_t)kNodes * kF * 2;          // ~19.9 MiB

typedef _Float16 f16x8 __attribute__((ext_vector_type(8)));
typedef float    f32x4 __attribute__((ext_vector_type(4)));

static __device__ __forceinline__ unsigned int packh2(float a, float b) {
    __half2 h = __floats2half2_rn(a, b);
    return *reinterpret_cast<unsigned int*>(&h);
}

// ---------------------------------------------------------------------------
// Kernel 0: zero bucket cursors (one per 64B line) + pack W into MFMA
// A-fragment order as f16.
// Fragment map for mfma_f32_16x16x32_f16, A-operand = W tile (16 outs x 32 k):
//   lane l, elem e -> row o_local = l&15, k_local = (l>>4)*8 + e
// Linear layout: Wf[(((nt*4)+ks)*64 + l)*8 + e], nt = o/16, ks = k/32.
__global__ __launch_bounds__(256) void prep0(const float* __restrict__ W,
                                             _Float16* __restrict__ Wf,
                                             int* __restrict__ cursor) {
    int gid = blockIdx.x * 256 + threadIdx.x;    // grid covers 50176
    if (gid < kF * kF) {
        int e  = gid & 7;
        int l  = (gid >> 3) & 63;
        int ks = (gid >> 9) & 3;
        int nt = gid >> 11;                      // 0..7
        int o  = nt * 16 + (l & 15);
        int k  = ks * 32 + ((l >> 4) & 3) * 8 + e;
        Wf[gid] = (_Float16)W[o * kF + k];
    }
    if (gid < kNodes) cursor[gid * kCurStride] = 0;   // only slot 0 of each line is used
}

// prep for the vestigial fallback path: fp32 W transpose
__global__ __launch_bounds__(256) void prep0_fb(const float* __restrict__ W,
                                                float* __restrict__ Wt,
                                                int* __restrict__ cursor) {
    int gid = blockIdx.x * 256 + threadIdx.x;
    if (gid < kF * kF) {
        int k = gid >> 7;
        int o = gid & (kF - 1);
        Wt[gid] = W[o * kF + k];
    }
    if (gid < kNodes) cursor[gid * kCurStride] = 0;
}

// ---------------------------------------------------------------------------
// Kernel F (R4: now a SEPARATE dispatch — was fused with gemm). Scatters src
// ids into dst buckets as ushort (src < 50000 < 2^16). Separation removes
// the L2 interference where the gemm's 38MB F/Gpk stream evicted
// partially-filled bucket lines mid-fill (R3 WRITE_SIZE showed ~23MB of
// write amplification), and gives per-phase rocprof rows.
// 4 edges/thread via int4 loads: 4 independent atomic chains in flight.
__global__ __launch_bounds__(256) void fill(const int* __restrict__ src,
                                            const int* __restrict__ dst,
                                            int* __restrict__ cursor,
                                            unsigned short* __restrict__ bucket) {
    const int gid = blockIdx.x * 256 + threadIdx.x;
    const int e0  = gid * kEPT;
    if (e0 + kEPT <= kEdges) {          // kEdges % 4 == 0 -> always full or none
        int4 d4 = *reinterpret_cast<const int4*>(dst + e0);
        int4 s4 = *reinterpret_cast<const int4*>(src + e0);
        int dd[4] = {d4.x, d4.y, d4.z, d4.w};
        int ss[4] = {s4.x, s4.y, s4.z, s4.w};
#pragma unroll
        for (int i = 0; i < kEPT; ++i) {
            int p = atomicAdd(&cursor[(size_t)dd[i] * kCurStride], 1);
            if (p < kCap) bucket[(size_t)dd[i] * kCap + p] = (unsigned short)ss[i];
        }
    } else if (e0 < kEdges) {
        for (int e = e0; e < kEdges; ++e) {
            int d = dst[e];
            int p = atomicAdd(&cursor[(size_t)d * kCurStride], 1);
            if (p < kCap) bucket[(size_t)d * kCap + p] = (unsigned short)src[e];
        }
    }
}

// ---------------------------------------------------------------------------
// Kernel G: G = F @ W^T via f16 MFMA with split-precision F (F = hi + lo,
// two MFMAs chained into the same f32 acc -> near-fp32 accuracy). LDS = 0:
// each wave owns 16 output rows, loads F global->reg directly (coalesced,
// F read exactly once). No __syncthreads.
// Fragment-layout note: A/B K-slot order is irrelevant (identical lane->K
// map on both operands + full-K sum => permutation-invariant). Only the
// lane&15 M/N mapping and the verified C/D map (row=(l>>4)*4+j, col=l&15)
// matter; W is fed as A (rows = outputs), F as B (cols = nodes), so each
// thread's 4 acc values are CONSECUTIVE output cols of one node -> packs
// straight into the Gpk2 uint2 layout.
__global__ __launch_bounds__(256) void gemm(const float* __restrict__ F,
                                            const _Float16* __restrict__ Wf,
                                            uint2* __restrict__ Gpk2) {
    const int t = threadIdx.x;
    const int b = blockIdx.x;

    const int n0  = b * kNPB;
    const int w   = t >> 6;                 // wave 0..3
    const int l   = t & 63;
    const int m0w = n0 + w * 16;
    if (m0w >= kNodes) return;              // last block: waves 1..3 fully OOB
    const int node  = m0w + (l & 15);       // B-operand col -> node
    const int nodeC = node < kNodes ? node : kNodes - 1;
    const int kbase = (l >> 4) * 8;         // this lane's K sub-chunk

    f32x4 acc[8];
#pragma unroll
    for (int nt = 0; nt < 8; ++nt) acc[nt] = (f32x4){0.f, 0.f, 0.f, 0.f};

    const f16x8* Wf8 = reinterpret_cast<const f16x8*>(Wf);

#pragma unroll
    for (int ks = 0; ks < 4; ++ks) {
        const float* fr = F + (size_t)nodeC * kF + ks * 32 + kbase;
        float4 x = *reinterpret_cast<const float4*>(fr);
        float4 y = *reinterpret_cast<const float4*>(fr + 4);
        float fv[8] = {x.x, x.y, x.z, x.w, y.x, y.y, y.z, y.w};
        f16x8 bhi, blo;
#pragma unroll
        for (int i = 0; i < 8; ++i) {
            _Float16 h = (_Float16)fv[i];
            bhi[i] = h;
            blo[i] = (_Float16)(fv[i] - (float)h);
        }
#pragma unroll
        for (int nt = 0; nt < 8; ++nt) {
            f16x8 af = Wf8[(nt * 4 + ks) * 64 + l];
            acc[nt] = __builtin_amdgcn_mfma_f32_16x16x32_f16(af, bhi, acc[nt], 0, 0, 0);
            acc[nt] = __builtin_amdgcn_mfma_f32_16x16x32_f16(af, blo, acc[nt], 0, 0, 0);
        }
    }

    if (node < kNodes) {
        // acc[nt][j] = G[node][nt*16 + (l>>4)*4 + j]  (C/D: row=o_local, col=node_local)
#pragma unroll
        for (int nt = 0; nt < 8; ++nt) {
            uint2 p;
            p.x = packh2(acc[nt][0], acc[nt][1]);
            p.y = packh2(acc[nt][2], acc[nt][3]);
            Gpk2[(size_t)node * 32 + nt * 4 + (l >> 4)] = p;
        }
    }
}

// ---------------------------------------------------------------------------
// Kernel 2: out[n] = tanh(sum_{e: dst=n} G[src_e] + b). One wave per node,
// 4 edge-groups x 16 lanes; lane reads uint4 = 8 fp16 cols. Edge ids are
// prefetched once per wave and broadcast via __shfl.
// CORRECTNESS NOTE: the j-loop is made WAVE-UNIFORM (iters = ceil(deg/4))
// so the ds_bpermute behind __shfl always executes with all 64 lanes active
// — bpermute from an EXEC-inactive source lane returns undefined data (this
// was R8's bug). Only the load+accumulate is predicated.
__global__ __launch_bounds__(256) void gather_tanh(const uint4* __restrict__ Gpk4,
                                                   const unsigned short* __restrict__ bucket,
                                                   const int* __restrict__ cursor,
                                                   const float* __restrict__ bias,
                                                   float* __restrict__ out) {
    const int wave = (blockIdx.x * 256 + threadIdx.x) >> 6;
    const int lane = threadIdx.x & 63;
    if (wave >= kNodes) return;
    const int grp = lane >> 4;      // 0..3 : edge group
    const int sub = lane & 15;      // 0..15 : cols [sub*8, sub*8+8)

    const int deg = min(cursor[(size_t)wave * kCurStride], kCap);
    const size_t base = (size_t)wave * kCap;

    // one coalesced load of all edge ids for this node (deg <= 48 < 64)
    int eid = (lane < deg) ? (int)bucket[base + lane] : 0;

    float acc[8];
#pragma unroll
    for (int i = 0; i < 8; ++i) acc[i] = 0.0f;

    const int iters = (deg + 3) >> 2;   // uniform across the wave
#pragma unroll 2
    for (int i = 0; i < iters; ++i) {
        const int j = grp + 4 * i;
        const bool valid = (j < deg);
        int s = __shfl(eid, valid ? j : 0);   // full exec mask -> defined
        if (valid) {
            uint4 u = Gpk4[(size_t)s * 16 + sub];       // 16B -> 8 fp16
            const __half2* hp = reinterpret_cast<const __half2*>(&u);
#pragma unroll
            for (int q = 0; q < 4; ++q) {
                float2 f = __half22float2(hp[q]);
                acc[2 * q]     += f.x;
                acc[2 * q + 1] += f.y;
            }
        }
    }

#pragma unroll
    for (int i = 0; i < 8; ++i) {
        acc[i] += __shfl_xor(acc[i], 16);
        acc[i] += __shfl_xor(acc[i], 32);
    }

    if (grp == 0) {
        float4 b0 = *reinterpret_cast<const float4*>(bias + sub * 8);
        float4 b1 = *reinterpret_cast<const float4*>(bias + sub * 8 + 4);
        float4 r0, r1;
        r0.x = 1.0f - 2.0f / (__expf(2.0f * (acc[0] + b0.x)) + 1.0f);
        r0.y = 1.0f - 2.0f / (__expf(2.0f * (acc[1] + b0.y)) + 1.0f);
        r0.z = 1.0f - 2.0f / (__expf(2.0f * (acc[2] + b0.z)) + 1.0f);
        r0.w = 1.0f - 2.0f / (__expf(2.0f * (acc[3] + b0.w)) + 1.0f);
        r1.x = 1.0f - 2.0f / (__expf(2.0f * (acc[4] + b1.x)) + 1.0f);
        r1.y = 1.0f - 2.0f / (__expf(2.0f * (acc[5] + b1.y)) + 1.0f);
        r1.z = 1.0f - 2.0f / (__expf(2.0f * (acc[6] + b1.z)) + 1.0f);
        r1.w = 1.0f - 2.0f / (__expf(2.0f * (acc[7] + b1.w)) + 1.0f);
        float4* dstp = reinterpret_cast<float4*>(out + (size_t)wave * kF + sub * 8);
        dstp[0] = r0;
        dstp[1] = r1;
    }
}

// ---------------------------------------------------------------------------
// Fallback (vestigial — measured ws_size is 256 MiB): R1-style atomic scatter.
__global__ __launch_bounds__(256) void scatter_add(const float* __restrict__ feature,
                                                   const int* __restrict__ src,
                                                   const int* __restrict__ dst,
                                                   float* __restrict__ agg) {
    int gid = blockIdx.x * 256 + threadIdx.x;
    int e = gid >> 5;
    int c = (gid & 31) << 2;
    float4 v = *reinterpret_cast<const float4*>(feature + (size_t)src[e] * kF + c);
    float* p = agg + (size_t)dst[e] * kF + c;
    atomicAdd(p + 0, v.x);
    atomicAdd(p + 1, v.y);
    atomicAdd(p + 2, v.z);
    atomicAdd(p + 3, v.w);
}

__global__ __launch_bounds__(256, 4) void linear_tanh(float* __restrict__ inout,
                                                      const float* __restrict__ Wt,
                                                      const float* __restrict__ bias) {
    __shared__ float sAgg[kNPB * kF];
    __shared__ float sB[kF];
    const int t  = threadIdx.x;
    const int n0 = blockIdx.x * kNPB;
    if (t < kF) sB[t] = bias[t];
    const int rows = min(kNPB, kNodes - n0);
    for (int i = t * 4; i < rows * kF; i += 256 * 4)
        *reinterpret_cast<float4*>(&sAgg[i]) =
            *reinterpret_cast<const float4*>(inout + (size_t)n0 * kF + i);
    __syncthreads();
    const int tn = t >> 5, to = t & 31, nb = tn * 8;
    float acc[8][4];
#pragma unroll
    for (int n = 0; n < 8; ++n)
#pragma unroll
        for (int j = 0; j < 4; ++j) acc[n][j] = 0.0f;
    for (int k = 0; k < kF; k += 4) {
        float4 wt[4];
#pragma unroll
        for (int i = 0; i < 4; ++i)
            wt[i] = *reinterpret_cast<const float4*>(Wt + (k + i) * kF + to * 4);
#pragma unroll
        for (int n = 0; n < 8; ++n) {
            float4 av = *reinterpret_cast<const float4*>(&sAgg[(nb + n) * kF + k]);
#pragma unroll
            for (int j = 0; j < 4; ++j) {
                const float* w0 = reinterpret_cast<const float*>(&wt[0]);
                const float* w1 = reinterpret_cast<const float*>(&wt[1]);
                const float* w2 = reinterpret_cast<const float*>(&wt[2]);
                const float* w3 = reinterpret_cast<const float*>(&wt[3]);
                acc[n][j] += av.x * w0[j] + av.y * w1[j] + av.z * w2[j] + av.w * w3[j];
            }
        }
    }
#pragma unroll
    for (int n = 0; n < 8; ++n) {
        int node = n0 + nb + n;
        if (node < kNodes) {
            float4 r;
            r.x = 1.0f - 2.0f / (__expf(2.0f * (acc[n][0] + sB[to * 4 + 0])) + 1.0f);
            r.y = 1.0f - 2.0f / (__expf(2.0f * (acc[n][1] + sB[to * 4 + 1])) + 1.0f);
            r.z = 1.0f - 2.0f / (__expf(2.0f * (acc[n][2] + sB[to * 4 + 2])) + 1.0f);
            r.w = 1.0f - 2.0f / (__expf(2.0f * (acc[n][3] + sB[to * 4 + 3])) + 1.0f);
            *reinterpret_cast<float4*>(inout + (size_t)node * kF + to * 4) = r;
        }
    }
}

// ---------------------------------------------------------------------------
extern "C" void kernel_launch(void* const* d_in, const int* in_sizes, int n_in,
                              void* d_out, int out_size, void* d_ws, size_t ws_size,
                              hipStream_t stream) {
    const float* feature = (const float*)d_in[0];
    const float* W       = (const float*)d_in[1];
    const float* b       = (const float*)d_in[2];
    const int*   src     = (const int*)d_in[3];
    const int*   dst     = (const int*)d_in[4];
    float* out = (float*)d_out;

    char* ws = (char*)d_ws;
    _Float16* Wfrag  = (_Float16*)(ws + kOffWt);
    float*    Wt     = (float*)(ws + kOffWt);
    int*      cursor = (int*)(ws + kOffCursor);
    unsigned short* bucket = (unsigned short*)(ws + kOffBucket);
    uint2*    Gpk2   = (uint2*)(ws + kOffGpk);

    if (ws_size >= kWsNeeded) {   // ws_size constant across calls -> graph-safe
        prep0<<<(kNodes + 255) / 256, 256, 0, stream>>>(W, Wfrag, cursor);
        fill<<<kFillB, 256, 0, stream>>>(src, dst, cursor, bucket);
        gemm<<<kGemmB, 256, 0, stream>>>(feature, Wfrag, Gpk2);
        gather_tanh<<<(kNodes + 3) / 4, 256, 0, stream>>>(
            (const uint4*)Gpk2, bucket, cursor, b, out);
    } else {
        prep0_fb<<<(kNodes + 255) / 256, 256, 0, stream>>>(W, Wt, cursor);
        hipMemsetAsync(out, 0, (size_t)kNodes * kF * sizeof(float), stream);
        scatter_add<<<(kEdges * 32) / 256, 256, 0, stream>>>(feature, src, dst, out);
        linear_tanh<<<(kNodes + kNPB - 1) / kNPB, 256, 0, stream>>>(out, Wt, b);
    }
}

// Round 5
// 143.771 us; speedup vs baseline: 1.1146x; 1.1146x over previous
//
#include <hip/hip_runtime.h>
#include <hip/hip_fp16.h>
#include <math.h>

constexpr int kNodes = 50000;
constexpr int kEdges = 600000;
constexpr int kF     = 128;
constexpr int kNPB   = 64;        // nodes per block in gemm phase (4 waves x 16)
constexpr int kCap   = 48;        // fixed bucket capacity; P(deg>=48) ~ 3e-15/node
constexpr int kCurStride = 16;    // one 64B cache line per cursor counter (R3, -3.5us)
constexpr int kEPT   = 4;         // edges per thread in fill (R4)

constexpr int kGemmB = (kNodes + kNPB - 1) / kNPB;               // 782
constexpr int kFillB = (kEdges + 256 * kEPT - 1) / (256 * kEPT); // 586
constexpr int kTotB  = kGemmB + kFillB;                          // 1368

// workspace layout (bytes)
constexpr size_t kOffWt     = 0;                                          // 64 KB region (Wfrag f16 = 32 KB)
constexpr size_t kOffCursor = 65536;                                      // 50000*64B = 3.2 MB padded counters
constexpr size_t kOffBucket = kOffCursor + (size_t)kNodes * kCurStride * 4; // ushort bucket, 4.8 MB
constexpr size_t kOffGpk    = kOffBucket + (size_t)kNodes * kCap * 2;     // 16B-aligned (4.8M%16==0)
constexpr size_t kWsNeeded  = kOffGpk + (size_t)kNodes * kF * 2;          // ~19.9 MiB

typedef _Float16 f16x8 __attribute__((ext_vector_type(8)));
typedef float    f32x4 __attribute__((ext_vector_type(4)));

static __device__ __forceinline__ unsigned int packh2(float a, float b) {
    __half2 h = __floats2half2_rn(a, b);
    return *reinterpret_cast<unsigned int*>(&h);
}

// ---------------------------------------------------------------------------
// Kernel 0: zero bucket cursors (one per 64B line) + pack W into MFMA
// A-fragment order as f16.
// Fragment map for mfma_f32_16x16x32_f16, A-operand = W tile (16 outs x 32 k):
//   lane l, elem e -> row o_local = l&15, k_local = (l>>4)*8 + e
// Linear layout: Wf[(((nt*4)+ks)*64 + l)*8 + e], nt = o/16, ks = k/32.
__global__ __launch_bounds__(256) void prep0(const float* __restrict__ W,
                                             _Float16* __restrict__ Wf,
                                             int* __restrict__ cursor) {
    int gid = blockIdx.x * 256 + threadIdx.x;    // grid covers 50176
    if (gid < kF * kF) {
        int e  = gid & 7;
        int l  = (gid >> 3) & 63;
        int ks = (gid >> 9) & 3;
        int nt = gid >> 11;                      // 0..7
        int o  = nt * 16 + (l & 15);
        int k  = ks * 32 + ((l >> 4) & 3) * 8 + e;
        Wf[gid] = (_Float16)W[o * kF + k];
    }
    if (gid < kNodes) cursor[gid * kCurStride] = 0;   // only slot 0 of each line is used
}

// prep for the vestigial fallback path: fp32 W transpose
__global__ __launch_bounds__(256) void prep0_fb(const float* __restrict__ W,
                                                float* __restrict__ Wt,
                                                int* __restrict__ cursor) {
    int gid = blockIdx.x * 256 + threadIdx.x;
    if (gid < kF * kF) {
        int k = gid >> 7;
        int o = gid & (kF - 1);
        Wt[gid] = W[o * kF + k];
    }
    if (gid < kNodes) cursor[gid * kCurStride] = 0;
}

// ---------------------------------------------------------------------------
// Kernel 1 (R5: re-fused, R0 ordering restored — gemm blocks [0,kGemmB)
// dispatch FIRST, fill blocks after, so the fill's ~35us atomic tail starts
// under the gemm (worth ~3-4us, measured R0 vs R4).
//
// GEMM phase: MFMA with split-precision F (F = hi+lo f16, two chained MFMAs
// into f32 acc). R2/R4 showed the naive MFMA version was LATENCY-bound at
// 60 VGPRs (JIT load scheduling, grid-limited 12 waves/CU). R5 restructure:
//  - all 8 F-loads issued upfront (independent, in flight together)
//  - W fragments double-buffered across the ks loop (load ks+1 while
//    MFMAing ks; 16 MFMAs ≈ 78cy < L1 latency, so prefetch is required)
//  - __launch_bounds__(256,3): VGPR cap 170 (design ~140), matching the
//    grid's natural 3 blocks/CU. No LDS anywhere in this kernel.
// Fragment-layout note: A/B K-slot order is irrelevant (identical lane->K
// map on both operands + full-K sum => permutation-invariant). Only the
// lane&15 M/N mapping and the verified C/D map (row=(l>>4)*4+j, col=l&15)
// matter.
//
// FILL phase: 4 edges/thread via int4; padded cursor (64B/counter); ushort
// bucket (src < 2^16). The ~35us fill wall has been flat against
// concurrency/padding/ordering across R0-R4 — treated as a device-scope
// atomic-pipe throughput limit pending contrary evidence.
__global__ __launch_bounds__(256, 3) void gemm_fill(const float* __restrict__ F,
                                                    const _Float16* __restrict__ Wf,
                                                    const int* __restrict__ src,
                                                    const int* __restrict__ dst,
                                                    int* __restrict__ cursor,
                                                    unsigned short* __restrict__ bucket,
                                                    uint2* __restrict__ Gpk2) {
    const int t = threadIdx.x;
    const int b = blockIdx.x;

    if (b >= kGemmB) {
        // ---- bucket-fill phase ----
        const int gid = (b - kGemmB) * 256 + t;
        const int e0  = gid * kEPT;
        if (e0 < kEdges) {                  // kEdges % 4 == 0 -> always a full quad
            int4 d4 = *reinterpret_cast<const int4*>(dst + e0);
            int4 s4 = *reinterpret_cast<const int4*>(src + e0);
            int dd[4] = {d4.x, d4.y, d4.z, d4.w};
            int ss[4] = {s4.x, s4.y, s4.z, s4.w};
#pragma unroll
            for (int i = 0; i < kEPT; ++i) {
                int p = atomicAdd(&cursor[(size_t)dd[i] * kCurStride], 1);
                if (p < kCap) bucket[(size_t)dd[i] * kCap + p] = (unsigned short)ss[i];
            }
        }
        return;
    }

    // ---- GEMM phase (per-wave independent 16-node strip) ----
    const int n0  = b * kNPB;
    const int w   = t >> 6;                 // wave 0..3
    const int l   = t & 63;
    const int m0w = n0 + w * 16;
    if (m0w >= kNodes) return;              // last block: waves 1..3 fully OOB
    const int node  = m0w + (l & 15);       // B-operand col -> node
    const int nodeC = node < kNodes ? node : kNodes - 1;
    const int kbase = (l >> 4) * 8;         // this lane's K sub-chunk

    const f16x8* Wf8 = reinterpret_cast<const f16x8*>(Wf);
    const float* frow = F + (size_t)nodeC * kF + kbase;

    // 1) issue ALL F loads upfront (8 independent dwordx4)
    float4 f4[8];
#pragma unroll
    for (int ks = 0; ks < 4; ++ks) {
        f4[ks * 2 + 0] = *reinterpret_cast<const float4*>(frow + ks * 32);
        f4[ks * 2 + 1] = *reinterpret_cast<const float4*>(frow + ks * 32 + 4);
    }

    // 2) issue first W slice (ks=0) while F converts
    f16x8 wq[8];
#pragma unroll
    for (int nt = 0; nt < 8; ++nt) wq[nt] = Wf8[(nt * 4 + 0) * 64 + l];

    // 3) split F into hi/lo f16
    f16x8 bhi[4], blo[4];
#pragma unroll
    for (int ks = 0; ks < 4; ++ks) {
        const float* fv0 = reinterpret_cast<const float*>(&f4[ks * 2]);
#pragma unroll
        for (int i = 0; i < 8; ++i) {
            float v = fv0[i];
            _Float16 h = (_Float16)v;
            bhi[ks][i] = h;
            blo[ks][i] = (_Float16)(v - (float)h);
        }
    }

    f32x4 acc[8];
#pragma unroll
    for (int nt = 0; nt < 8; ++nt) acc[nt] = (f32x4){0.f, 0.f, 0.f, 0.f};

    // 4) ks loop: MFMA current W slice while prefetching the next
#pragma unroll
    for (int ks = 0; ks < 4; ++ks) {
        f16x8 wn[8];
        if (ks < 3) {
#pragma unroll
            for (int nt = 0; nt < 8; ++nt) wn[nt] = Wf8[(nt * 4 + ks + 1) * 64 + l];
        }
#pragma unroll
        for (int nt = 0; nt < 8; ++nt) {
            acc[nt] = __builtin_amdgcn_mfma_f32_16x16x32_f16(wq[nt], bhi[ks], acc[nt], 0, 0, 0);
            acc[nt] = __builtin_amdgcn_mfma_f32_16x16x32_f16(wq[nt], blo[ks], acc[nt], 0, 0, 0);
        }
        if (ks < 3) {
#pragma unroll
            for (int nt = 0; nt < 8; ++nt) wq[nt] = wn[nt];
        }
    }

    if (node < kNodes) {
        // acc[nt][j] = G[node][nt*16 + (l>>4)*4 + j]  (C/D: row=o_local, col=node_local)
#pragma unroll
        for (int nt = 0; nt < 8; ++nt) {
            uint2 p;
            p.x = packh2(acc[nt][0], acc[nt][1]);
            p.y = packh2(acc[nt][2], acc[nt][3]);
            Gpk2[(size_t)node * 32 + nt * 4 + (l >> 4)] = p;
        }
    }
}

// ---------------------------------------------------------------------------
// Kernel 2: out[n] = tanh(sum_{e: dst=n} G[src_e] + b). One wave per node,
// 4 edge-groups x 16 lanes; lane reads uint4 = 8 fp16 cols. Edge ids are
// prefetched once per wave and broadcast via __shfl.
// CORRECTNESS NOTE: the j-loop is made WAVE-UNIFORM (iters = ceil(deg/4))
// so the ds_bpermute behind __shfl always executes with all 64 lanes active
// — bpermute from an EXEC-inactive source lane returns undefined data (this
// was R8's bug). Only the load+accumulate is predicated.
__global__ __launch_bounds__(256) void gather_tanh(const uint4* __restrict__ Gpk4,
                                                   const unsigned short* __restrict__ bucket,
                                                   const int* __restrict__ cursor,
                                                   const float* __restrict__ bias,
                                                   float* __restrict__ out) {
    const int wave = (blockIdx.x * 256 + threadIdx.x) >> 6;
    const int lane = threadIdx.x & 63;
    if (wave >= kNodes) return;
    const int grp = lane >> 4;      // 0..3 : edge group
    const int sub = lane & 15;      // 0..15 : cols [sub*8, sub*8+8)

    const int deg = min(cursor[(size_t)wave * kCurStride], kCap);
    const size_t base = (size_t)wave * kCap;

    // one coalesced load of all edge ids for this node (deg <= 48 < 64)
    int eid = (lane < deg) ? (int)bucket[base + lane] : 0;

    float acc[8];
#pragma unroll
    for (int i = 0; i < 8; ++i) acc[i] = 0.0f;

    const int iters = (deg + 3) >> 2;   // uniform across the wave
#pragma unroll 2
    for (int i = 0; i < iters; ++i) {
        const int j = grp + 4 * i;
        const bool valid = (j < deg);
        int s = __shfl(eid, valid ? j : 0);   // full exec mask -> defined
        if (valid) {
            uint4 u = Gpk4[(size_t)s * 16 + sub];       // 16B -> 8 fp16
            const __half2* hp = reinterpret_cast<const __half2*>(&u);
#pragma unroll
            for (int q = 0; q < 4; ++q) {
                float2 f = __half22float2(hp[q]);
                acc[2 * q]     += f.x;
                acc[2 * q + 1] += f.y;
            }
        }
    }

#pragma unroll
    for (int i = 0; i < 8; ++i) {
        acc[i] += __shfl_xor(acc[i], 16);
        acc[i] += __shfl_xor(acc[i], 32);
    }

    if (grp == 0) {
        float4 b0 = *reinterpret_cast<const float4*>(bias + sub * 8);
        float4 b1 = *reinterpret_cast<const float4*>(bias + sub * 8 + 4);
        float4 r0, r1;
        r0.x = 1.0f - 2.0f / (__expf(2.0f * (acc[0] + b0.x)) + 1.0f);
        r0.y = 1.0f - 2.0f / (__expf(2.0f * (acc[1] + b0.y)) + 1.0f);
        r0.z = 1.0f - 2.0f / (__expf(2.0f * (acc[2] + b0.z)) + 1.0f);
        r0.w = 1.0f - 2.0f / (__expf(2.0f * (acc[3] + b0.w)) + 1.0f);
        r1.x = 1.0f - 2.0f / (__expf(2.0f * (acc[4] + b1.x)) + 1.0f);
        r1.y = 1.0f - 2.0f / (__expf(2.0f * (acc[5] + b1.y)) + 1.0f);
        r1.z = 1.0f - 2.0f / (__expf(2.0f * (acc[6] + b1.z)) + 1.0f);
        r1.w = 1.0f - 2.0f / (__expf(2.0f * (acc[7] + b1.w)) + 1.0f);
        float4* dstp = reinterpret_cast<float4*>(out + (size_t)wave * kF + sub * 8);
        dstp[0] = r0;
        dstp[1] = r1;
    }
}

// ---------------------------------------------------------------------------
// Fallback (vestigial — measured ws_size is 256 MiB): R1-style atomic scatter.
__global__ __launch_bounds__(256) void scatter_add(const float* __restrict__ feature,
                                                   const int* __restrict__ src,
                                                   const int* __restrict__ dst,
                                                   float* __restrict__ agg) {
    int gid = blockIdx.x * 256 + threadIdx.x;
    int e = gid >> 5;
    int c = (gid & 31) << 2;
    float4 v = *reinterpret_cast<const float4*>(feature + (size_t)src[e] * kF + c);
    float* p = agg + (size_t)dst[e] * kF + c;
    atomicAdd(p + 0, v.x);
    atomicAdd(p + 1, v.y);
    atomicAdd(p + 2, v.z);
    atomicAdd(p + 3, v.w);
}

__global__ __launch_bounds__(256, 4) void linear_tanh(float* __restrict__ inout,
                                                      const float* __restrict__ Wt,
                                                      const float* __restrict__ bias) {
    __shared__ float sAgg[kNPB * kF];
    __shared__ float sB[kF];
    const int t  = threadIdx.x;
    const int n0 = blockIdx.x * kNPB;
    if (t < kF) sB[t] = bias[t];
    const int rows = min(kNPB, kNodes - n0);
    for (int i = t * 4; i < rows * kF; i += 256 * 4)
        *reinterpret_cast<float4*>(&sAgg[i]) =
            *reinterpret_cast<const float4*>(inout + (size_t)n0 * kF + i);
    __syncthreads();
    const int tn = t >> 5, to = t & 31, nb = tn * 8;
    float acc[8][4];
#pragma unroll
    for (int n = 0; n < 8; ++n)
#pragma unroll
        for (int j = 0; j < 4; ++j) acc[n][j] = 0.0f;
    for (int k = 0; k < kF; k += 4) {
        float4 wt[4];
#pragma unroll
        for (int i = 0; i < 4; ++i)
            wt[i] = *reinterpret_cast<const float4*>(Wt + (k + i) * kF + to * 4);
#pragma unroll
        for (int n = 0; n < 8; ++n) {
            float4 av = *reinterpret_cast<const float4*>(&sAgg[(nb + n) * kF + k]);
#pragma unroll
            for (int j = 0; j < 4; ++j) {
                const float* w0 = reinterpret_cast<const float*>(&wt[0]);
                const float* w1 = reinterpret_cast<const float*>(&wt[1]);
                const float* w2 = reinterpret_cast<const float*>(&wt[2]);
                const float* w3 = reinterpret_cast<const float*>(&wt[3]);
                acc[n][j] += av.x * w0[j] + av.y * w1[j] + av.z * w2[j] + av.w * w3[j];
            }
        }
    }
#pragma unroll
    for (int n = 0; n < 8; ++n) {
        int node = n0 + nb + n;
        if (node < kNodes) {
            float4 r;
            r.x = 1.0f - 2.0f / (__expf(2.0f * (acc[n][0] + sB[to * 4 + 0])) + 1.0f);
            r.y = 1.0f - 2.0f / (__expf(2.0f * (acc[n][1] + sB[to * 4 + 1])) + 1.0f);
            r.z = 1.0f - 2.0f / (__expf(2.0f * (acc[n][2] + sB[to * 4 + 2])) + 1.0f);
            r.w = 1.0f - 2.0f / (__expf(2.0f * (acc[n][3] + sB[to * 4 + 3])) + 1.0f);
            *reinterpret_cast<float4*>(inout + (size_t)node * kF + to * 4) = r;
        }
    }
}

// ---------------------------------------------------------------------------
extern "C" void kernel_launch(void* const* d_in, const int* in_sizes, int n_in,
                              void* d_out, int out_size, void* d_ws, size_t ws_size,
                              hipStream_t stream) {
    const float* feature = (const float*)d_in[0];
    const float* W       = (const float*)d_in[1];
    const float* b       = (const float*)d_in[2];
    const int*   src     = (const int*)d_in[3];
    const int*   dst     = (const int*)d_in[4];
    float* out = (float*)d_out;

    char* ws = (char*)d_ws;
    _Float16* Wfrag  = (_Float16*)(ws + kOffWt);
    float*    Wt     = (float*)(ws + kOffWt);
    int*      cursor = (int*)(ws + kOffCursor);
    unsigned short* bucket = (unsigned short*)(ws + kOffBucket);
    uint2*    Gpk2   = (uint2*)(ws + kOffGpk);

    if (ws_size >= kWsNeeded) {   // ws_size constant across calls -> graph-safe
        prep0<<<(kNodes + 255) / 256, 256, 0, stream>>>(W, Wfrag, cursor);
        gemm_fill<<<kTotB, 256, 0, stream>>>(
            feature, Wfrag, src, dst, cursor, bucket, Gpk2);
        gather_tanh<<<(kNodes + 3) / 4, 256, 0, stream>>>(
            (const uint4*)Gpk2, bucket, cursor, b, out);
    } else {
        prep0_fb<<<(kNodes + 255) / 256, 256, 0, stream>>>(W, Wt, cursor);
        hipMemsetAsync(out, 0, (size_t)kNodes * kF * sizeof(float), stream);
        scatter_add<<<(kEdges * 32) / 256, 256, 0, stream>>>(feature, src, dst, out);
        linear_tanh<<<(kNodes + kNPB - 1) / kNPB, 256, 0, stream>>>(out, Wt, b);
    }
}